// Round 13
// baseline (88.327 us; speedup 1.0000x reference)
//
#include <hip/hip_runtime.h>
#include <cfloat>
#include <cmath>

// Problem constants (from reference)
#define Nn 32
#define Qq 300
#define Cc 92
#define Tt 32
#define KCOLS 5     // ceil(300/64) columns owned per lane
#define LSTRIDE 93  // LDS logits row stride (dwords); 93%32=29 coprime -> conflict-free
#define AUCTION_ROUNDS 6   // rounds 1-2 assign ~30/32 rows; later rounds are
                           // epsilon-free price wars (delta~0) -> Dijkstra wins

// ---------------------------------------------------------------------------
// DPP full-wave (64-lane) float min, broadcast to all lanes (~6 dep. v_min).
// ---------------------------------------------------------------------------
__device__ inline float wave_min_bcast(float x) {
#define DPPMIN(ctrl) { int _t = __builtin_amdgcn_update_dpp( \
        __float_as_int(x), __float_as_int(x), ctrl, 0xf, 0xf, false); \
        x = fminf(x, __int_as_float(_t)); }
    DPPMIN(0x111) DPPMIN(0x112) DPPMIN(0x114) DPPMIN(0x118)
    DPPMIN(0x142) DPPMIN(0x143)
#undef DPPMIN
    return __int_as_float(__builtin_amdgcn_readlane(__float_as_int(x), 63));
}

// Select a[k] for runtime k (cndmask chain, no scratch).
__device__ inline int sel5i(const int a[KCOLS], int k) {
    int r = a[0];
    if (k == 1) r = a[1];
    if (k == 2) r = a[2];
    if (k == 3) r = a[3];
    if (k == 4) r = a[4];
    return r;
}

__device__ inline float readlane_f(float v, int lane) {
    return __int_as_float(__builtin_amdgcn_readlane(__float_as_int(v), lane));
}

// STREAMING two-pass softmax over an LDS row (no 92-float register array ->
// no scratch spill). 4 partial accumulators for BOTH max and sum (shorter
// dependency chains; fmaxf is associative+commutative -> mx bit-identical).
// Same helper in phase A and C: mx/inv_s bit-identical.
__device__ inline void softmax_lds(const float* __restrict__ srow,
                                   float& mx, float& inv_s) {
    float m0 = -FLT_MAX, m1 = -FLT_MAX, m2 = -FLT_MAX, m3 = -FLT_MAX;
#pragma unroll
    for (int c = 0; c < Cc; c += 4) {
        m0 = fmaxf(m0, srow[c + 0]);
        m1 = fmaxf(m1, srow[c + 1]);
        m2 = fmaxf(m2, srow[c + 2]);
        m3 = fmaxf(m3, srow[c + 3]);
    }
    const float m = fmaxf(fmaxf(m0, m1), fmaxf(m2, m3));
    float s0 = 0.f, s1 = 0.f, s2 = 0.f, s3 = 0.f;
#pragma unroll
    for (int c = 0; c < Cc; c += 4) {
        s0 += __expf(srow[c + 0] - m);
        s1 += __expf(srow[c + 1] - m);
        s2 += __expf(srow[c + 2] - m);
        s3 += __expf(srow[c + 3] - m);
    }
    mx = m; inv_s = 1.f / ((s0 + s1) + (s2 + s3));
}

// cost = 5*L1 + cls - 2*giou   (cls = -softmax_prob[label], passed in)
__device__ inline float det_cost(float cx, float cy, float w, float h,
                                 float bcx, float bcy, float bw, float bh,
                                 float cls) {
    const float ax0 = cx - 0.5f * w, ay0 = cy - 0.5f * h;
    const float ax1 = cx + 0.5f * w, ay1 = cy + 0.5f * h;
    const float areaA = (ax1 - ax0) * (ay1 - ay0);

    const float l1 = fabsf(cx - bcx) + fabsf(cy - bcy) +
                     fabsf(w - bw) + fabsf(h - bh);

    const float bx0 = bcx - 0.5f * bw, by0 = bcy - 0.5f * bh;
    const float bx1 = bcx + 0.5f * bw, by1 = bcy + 0.5f * bh;
    const float areaB = (bx1 - bx0) * (by1 - by0);

    const float ltx = fmaxf(ax0, bx0), lty = fmaxf(ay0, by0);
    const float rbx = fminf(ax1, bx1), rby = fminf(ay1, by1);
    const float iw = fmaxf(rbx - ltx, 0.f), ih = fmaxf(rby - lty, 0.f);
    const float inter = iw * ih;
    const float uni = areaA + areaB - inter;
    const float iou = inter / uni;

    const float ex0 = fminf(ax0, bx0), ey0 = fminf(ay0, by0);
    const float ex1 = fmaxf(ax1, bx1), ey1 = fmaxf(ay1, by1);
    const float areaC = fmaxf(ex1 - ex0, 0.f) * fmaxf(ey1 - ey0, 0.f);
    const float giou = iou - (areaC - uni) / areaC;

    return 5.f * l1 + cls - 2.f * giou;
}

// ---------------------------------------------------------------------------
// Fused kernel: one block per batch.
//  Phase 0: stage logits slice -> LDS (dense coalesced float4).
//  Phase A: diag cost block -> LDS (streaming softmax).
//  Phase B1 (ALL 5 waves): Jacobi parallel auction, CAPPED at 6 rounds and
//    early-exits when <=2 rows remain (r12 post-mortem: uncapped rounds stall
//    in epsilon-free price wars and burned ~20us). Invariants: v only
//    decreases, assigned edges tight, duals feasible -> any prefix of rounds
//    leaves a valid warm start for the exact fallback.
//  Phase B2 (wave 0): r11 deferred-dual Dijkstra for the leftovers (exact).
//  Phase C (lanes 0-31): 32 matched CROSS costs (reference quirk:
//    mult[i, q_of_t, arange(T)] gathers against GLOBAL targets 0..31).
// ---------------------------------------------------------------------------
__global__ __launch_bounds__(320) void fused_kernel(
    const float* __restrict__ logits,   // [N,Q,C]
    const float* __restrict__ pboxes,   // [N,Q,4]
    const int*   __restrict__ tlabels,  // [N*T]
    const float* __restrict__ tboxes,   // [N*T,4]
    float* __restrict__ out)            // scalar accumulator (pre-zeroed)
{
    const int b = blockIdx.x;
    const int tid = threadIdx.x;

    extern __shared__ float s_lg[];     // [Qq][LSTRIDE] padded logits, 111600 B
    __shared__ float s_diag[Tt * Qq];   // 38400 B, [t][q]
    __shared__ float s_tb[Tt * 4];      // batch-b targets
    __shared__ int   s_tl[Tt];
    __shared__ int   pairs[Tt];         // q_of_t
    __shared__ float s_v[Qq];           // column duals
    __shared__ float s_u[Tt + 1];       // row duals (1-based)
    __shared__ int   s_colrow[Qq];      // row (1..32) matched to col, 0=free
    __shared__ unsigned s_bid[Qq];      // float-bits(delta)+1, 0=empty
    __shared__ int   s_bidrow[Qq];      // winning row id per column
    __shared__ unsigned s_mask;         // bit (i-1) -> row i unassigned

    if (tid < Tt * 4) s_tb[tid] = tboxes[b * Tt * 4 + tid];
    if (tid < Tt)     s_tl[tid] = tlabels[b * Tt + tid];
    if (tid < Qq)     { s_v[tid] = 0.f; s_colrow[tid] = 0; }
    if (tid == 0)     s_mask = 0xffffffffu;   // all 32 rows unassigned

    // ---------------- Phase 0: coalesced logits -> LDS ----------------
    {
        const float4* lgb = reinterpret_cast<const float4*>(
            logits + (size_t)b * Qq * Cc);
#pragma unroll 4
        for (int g = tid; g < Qq * 23; g += 320) {
            const float4 v = lgb[g];
            const int r = g / 23, c4 = (g - r * 23) * 4;
            float* dst = &s_lg[r * LSTRIDE + c4];
            dst[0] = v.x; dst[1] = v.y; dst[2] = v.z; dst[3] = v.w;
        }
    }
    __syncthreads();

    // ---------------- Phase A: diag costs into LDS ----------------
    if (tid < Qq) {
        const float* srow = &s_lg[tid * LSTRIDE];
        float mx, inv_s;
        softmax_lds(srow, mx, inv_s);
        const float4 pbv = reinterpret_cast<const float4*>(pboxes)[b * Qq + tid];
#pragma unroll 4
        for (int t = 0; t < Tt; ++t) {
            const float cls = -__expf(srow[s_tl[t]] - mx) * inv_s;
            s_diag[t * Qq + tid] =
                det_cost(pbv.x, pbv.y, pbv.z, pbv.w,
                         s_tb[t * 4 + 0], s_tb[t * 4 + 1],
                         s_tb[t * 4 + 2], s_tb[t * 4 + 3], cls);
        }
    }
    __syncthreads();

    // ------------- Phase B1: parallel auction (all 320 threads) -------------
    {
        const int w = tid >> 6, ln = tid & 63;
        const bool iv4 = (ln + 256) >= Qq;
        for (int round = 0; round < AUCTION_ROUNDS; ++round) {
            const unsigned msk = s_mask;        // uniform (read after barrier)
            if (msk == 0 || __popc(msk) <= 2) break;  // leftovers -> Dijkstra
            if (tid < Qq) { s_bid[tid] = 0u; s_bidrow[tid] = 0xffff; }
            __syncthreads();

            // wave w takes the w-th set bit of msk (w <= 4 pops)
            int row = 0;
            { unsigned m = msk; int cnt = w;
              while (m && cnt) { m &= m - 1; --cnt; }
              if (m) row = __ffs(m); }          // 1..32, 0 = idle wave

            float g1 = 0.f, g2 = 0.f; int j1 = 0; unsigned mybid = 0;
            if (row) {
                const float* rowp = &s_diag[(row - 1) * Qq + ln];
                float m1 = INFINITY, m2 = INFINITY; int a1 = 0;
                float c;
                c = rowp[0]   - s_v[ln];
                if (c < m1) { m2 = m1; m1 = c; a1 = ln + 1; }   else if (c < m2) m2 = c;
                c = rowp[64]  - s_v[ln + 64];
                if (c < m1) { m2 = m1; m1 = c; a1 = ln + 65; }  else if (c < m2) m2 = c;
                c = rowp[128] - s_v[ln + 128];
                if (c < m1) { m2 = m1; m1 = c; a1 = ln + 129; } else if (c < m2) m2 = c;
                c = rowp[192] - s_v[ln + 192];
                if (c < m1) { m2 = m1; m1 = c; a1 = ln + 193; } else if (c < m2) m2 = c;
                c = iv4 ? INFINITY : (rowp[256] - s_v[ln + 256]);
                if (c < m1) { m2 = m1; m1 = c; a1 = ln + 257; } else if (c < m2) m2 = c;

                g1 = wave_min_bcast(m1);
                const unsigned long long mk = __ballot(m1 == g1);
                const int src = __ffsll((long long)mk) - 1;
                const float cand2 = (ln == src) ? m2 : m1;  // global 2nd min
                g2 = wave_min_bcast(cand2);
                j1 = __builtin_amdgcn_readlane(a1, src);
                mybid = __float_as_uint(g2 - g1) + 1u;      // delta>=0: bits monotone
                if (ln == 0) atomicMax(&s_bid[j1 - 1], mybid);
            }
            __syncthreads();
            if (row && ln == 0 && s_bid[j1 - 1] == mybid)
                atomicMin(&s_bidrow[j1 - 1], row);
            __syncthreads();
            if (row && ln == 0) {
                if (s_bid[j1 - 1] == mybid && s_bidrow[j1 - 1] == row) {
                    const int old = s_colrow[j1 - 1];       // unique winner/col
                    s_colrow[j1 - 1] = row;
                    s_v[j1 - 1] -= (g2 - g1);
                    s_u[row] = g2;                          // tight + feasible
                    atomicAnd(&s_mask, ~(1u << (row - 1)));
                    if (old) atomicOr(&s_mask, 1u << (old - 1));
                } else {
                    s_u[row] = g1;                          // feasible for fallback
                }
            }
            __syncthreads();
        }
    }

    if (tid >= 64) return;            // waves 1-4 done; wave 0 below
    const int lane = tid;
    const bool inval4 = (lane + 256) >= Qq;

    // load duals/matching into wave-0 registers
    float u_reg = (lane >= 1 && lane <= Tt) ? s_u[lane] : 0.f;
    float v_r[KCOLS]; int p_r[KCOLS];
#pragma unroll
    for (int k = 0; k < KCOLS; ++k) {
        const int j = lane + 64 * k;
        v_r[k] = (j < Qq) ? s_v[j] : 0.f;
        p_r[k] = (j < Qq) ? s_colrow[j] : 0;
    }

    // ---- Phase B2: Dijkstra fallback (r11 engine) for any leftovers ----
    for (unsigned rem = s_mask; rem; rem &= rem - 1) {
        const int i = __ffs(rem);     // row index 1..32

        float minv_r[KCOLS], vmask[KCOLS], am[KCOLS];
        int way_r[KCOLS];
#pragma unroll
        for (int k = 0; k < KCOLS; ++k) {
            minv_r[k] = FLT_MAX; way_r[k] = 0;
            const bool inv = (k == 4) && inval4;
            vmask[k] = inv ? -INFINITY : v_r[k];
            am[k]    = inv ?  INFINITY : 0.f;
        }
        float markg = 0.f;
        int   ent = 0;
        int   j0 = 0, i0 = i;
        float du = 0.f - readlane_f(u_reg, i);   // dent(0) - u[i]
        int   jfinal = 0;
        float Dfinal = 0.f;

        const float* rowp = &s_diag[(i0 - 1) * Qq + lane];
        float c0 = rowp[0], c1 = rowp[64], c2 = rowp[128], c3 = rowp[192],
              c4 = rowp[256];

        while (true) {
            const float cc[KCOLS] = {c0, c1, c2, c3, c4};
            float sv[KCOLS];
#pragma unroll
            for (int k = 0; k < KCOLS; ++k) {
                const float cur = (cc[k] + du) - vmask[k];  // used/invalid -> +inf
                const bool lt = cur < minv_r[k];
                way_r[k]  = lt ? j0  : way_r[k];
                minv_r[k] = lt ? cur : minv_r[k];
                sv[k] = minv_r[k] + am[k];
            }
            float val = sv[0];
            int   kb  = 0;
#pragma unroll
            for (int k = 1; k < KCOLS; ++k)
                if (sv[k] < val) { val = sv[k]; kb = k; }

            const float gmin = wave_min_bcast(val);
            const unsigned long long mask = __ballot(val == gmin);
            const int src = __ffsll((long long)mask) - 1;
            const int colid = lane + 1 + (kb << 6);
            const int pk = (sel5i(p_r, kb) << 16) | colid;
            const int got = __builtin_amdgcn_readlane(pk, src);
            const int j1   = got & 0xffff;
            const int rowm = got >> 16;

            const int k1 = (j1 - 1) >> 6;
            const bool own = (lane == ((j1 - 1) & 63));
#pragma unroll
            for (int k = 0; k < KCOLS; ++k)
                if (own && k == k1) { vmask[k] = -INFINITY; am[k] = INFINITY; }

            if (rowm == 0) { jfinal = j1; Dfinal = gmin; break; }

            i0 = rowm; j0 = j1;
            rowp = &s_diag[(i0 - 1) * Qq + lane];
            c0 = rowp[0]; c1 = rowp[64]; c2 = rowp[128]; c3 = rowp[192];
            c4 = rowp[256];
            du = gmin - readlane_f(u_reg, i0);
            markg = (lane == rowm) ? gmin : markg;
            ent   = (lane == rowm) ? 1    : ent;
        }

#pragma unroll
        for (int k = 0; k < KCOLS; ++k) {
            bool usedk = (am[k] == INFINITY);
            if (k == 4) usedk = usedk && !inval4;
            v_r[k] -= usedk ? (Dfinal - minv_r[k]) : 0.f;
        }
        u_reg += (lane == i) ? Dfinal : (ent ? (Dfinal - markg) : 0.f);

        int jj = jfinal;
        while (jj) {
            const int ow = (jj - 1) & 63, kk = (jj - 1) >> 6;
            const int jprev = __builtin_amdgcn_readlane(sel5i(way_r, kk), ow);
            int pnew;
            if (jprev == 0) pnew = i;
            else pnew = __builtin_amdgcn_readlane(sel5i(p_r, (jprev - 1) >> 6),
                                                  (jprev - 1) & 63);
            const bool own = (lane == ow);
#pragma unroll
            for (int k = 0; k < KCOLS; ++k) if (own && k == kk) p_r[k] = pnew;
            jj = jprev;
        }
    }

    // publish assignment: q_of_t
#pragma unroll
    for (int k = 0; k < KCOLS; ++k)
        if (p_r[k]) pairs[p_r[k] - 1] = lane + 64 * k;
    __threadfence_block();

    // ---------------- Phase C: 32 matched cross costs ----------------
    float part = 0.f;
    if (lane < Tt) {
        const int q = pairs[lane];                        // matched query
        const float* srow = &s_lg[q * LSTRIDE];
        float mx, inv_s;
        softmax_lds(srow, mx, inv_s);                      // identical path to phase A
        const float4 pbv = reinterpret_cast<const float4*>(pboxes)[b * Qq + q];
        const float4 tbv = reinterpret_cast<const float4*>(tboxes)[lane];  // GLOBAL t=lane
        const float cls = -__expf(srow[tlabels[lane]] - mx) * inv_s;
        part = det_cost(pbv.x, pbv.y, pbv.z, pbv.w,
                        tbv.x, tbv.y, tbv.z, tbv.w, cls);
    }
    for (int off = 32; off > 0; off >>= 1) part += __shfl_down(part, off);
    if (lane == 0) atomicAdd(out, part);
}

extern "C" void kernel_launch(void* const* d_in, const int* in_sizes, int n_in,
                              void* d_out, int out_size, void* d_ws, size_t ws_size,
                              hipStream_t stream) {
    const float* logits  = (const float*)d_in[0];   // [32,300,92] f32
    const float* pboxes  = (const float*)d_in[1];   // [32,300,4]  f32
    const int*   tlabels = (const int*)d_in[2];     // [1024]      int
    const float* tboxes  = (const float*)d_in[3];   // [1024,4]    f32
    float* out = (float*)d_out;                     // scalar f32

    (void)hipMemsetAsync(out, 0, sizeof(float), stream);
    const size_t lg_bytes = (size_t)Qq * LSTRIDE * sizeof(float);  // 111600 B
    fused_kernel<<<Nn, 320, lg_bytes, stream>>>(logits, pboxes, tlabels, tboxes, out);
}

// Round 14
// 83.551 us; speedup vs baseline: 1.0572x; 1.0572x over previous
//
#include <hip/hip_runtime.h>
#include <cfloat>
#include <cmath>

// Problem constants (from reference)
#define Nn 32
#define Qq 300
#define Cc 92
#define Tt 32
#define KCOLS 5     // ceil(300/64) columns owned per lane
#define LSTRIDE 93  // LDS logits row stride (dwords); 93%32=29 coprime -> conflict-free
#define AUCTION_ROUNDS 16  // full-width rounds: round 1 scans ALL rows

// ---------------------------------------------------------------------------
// DPP full-wave (64-lane) float min, broadcast to all lanes (~6 dep. v_min).
// ---------------------------------------------------------------------------
__device__ inline float wave_min_bcast(float x) {
#define DPPMIN(ctrl) { int _t = __builtin_amdgcn_update_dpp( \
        __float_as_int(x), __float_as_int(x), ctrl, 0xf, 0xf, false); \
        x = fminf(x, __int_as_float(_t)); }
    DPPMIN(0x111) DPPMIN(0x112) DPPMIN(0x114) DPPMIN(0x118)
    DPPMIN(0x142) DPPMIN(0x143)
#undef DPPMIN
    return __int_as_float(__builtin_amdgcn_readlane(__float_as_int(x), 63));
}

// Select a[k] for runtime k (cndmask chain, no scratch).
__device__ inline int sel5i(const int a[KCOLS], int k) {
    int r = a[0];
    if (k == 1) r = a[1];
    if (k == 2) r = a[2];
    if (k == 3) r = a[3];
    if (k == 4) r = a[4];
    return r;
}

__device__ inline float readlane_f(float v, int lane) {
    return __int_as_float(__builtin_amdgcn_readlane(__float_as_int(v), lane));
}

// STREAMING two-pass softmax over an LDS row (no 92-float register array ->
// no scratch spill). 4 partial accumulators for BOTH max and sum. Same helper
// in phase A and C: mx/inv_s bit-identical.
__device__ inline void softmax_lds(const float* __restrict__ srow,
                                   float& mx, float& inv_s) {
    float m0 = -FLT_MAX, m1 = -FLT_MAX, m2 = -FLT_MAX, m3 = -FLT_MAX;
#pragma unroll
    for (int c = 0; c < Cc; c += 4) {
        m0 = fmaxf(m0, srow[c + 0]);
        m1 = fmaxf(m1, srow[c + 1]);
        m2 = fmaxf(m2, srow[c + 2]);
        m3 = fmaxf(m3, srow[c + 3]);
    }
    const float m = fmaxf(fmaxf(m0, m1), fmaxf(m2, m3));
    float s0 = 0.f, s1 = 0.f, s2 = 0.f, s3 = 0.f;
#pragma unroll
    for (int c = 0; c < Cc; c += 4) {
        s0 += __expf(srow[c + 0] - m);
        s1 += __expf(srow[c + 1] - m);
        s2 += __expf(srow[c + 2] - m);
        s3 += __expf(srow[c + 3] - m);
    }
    mx = m; inv_s = 1.f / ((s0 + s1) + (s2 + s3));
}

// cost = 5*L1 + cls - 2*giou   (cls = -softmax_prob[label], passed in)
__device__ inline float det_cost(float cx, float cy, float w, float h,
                                 float bcx, float bcy, float bw, float bh,
                                 float cls) {
    const float ax0 = cx - 0.5f * w, ay0 = cy - 0.5f * h;
    const float ax1 = cx + 0.5f * w, ay1 = cy + 0.5f * h;
    const float areaA = (ax1 - ax0) * (ay1 - ay0);

    const float l1 = fabsf(cx - bcx) + fabsf(cy - bcy) +
                     fabsf(w - bw) + fabsf(h - bh);

    const float bx0 = bcx - 0.5f * bw, by0 = bcy - 0.5f * bh;
    const float bx1 = bcx + 0.5f * bw, by1 = bcy + 0.5f * bh;
    const float areaB = (bx1 - bx0) * (by1 - by0);

    const float ltx = fmaxf(ax0, bx0), lty = fmaxf(ay0, by0);
    const float rbx = fminf(ax1, bx1), rby = fminf(ay1, by1);
    const float iw = fmaxf(rbx - ltx, 0.f), ih = fmaxf(rby - lty, 0.f);
    const float inter = iw * ih;
    const float uni = areaA + areaB - inter;
    const float iou = inter / uni;

    const float ex0 = fminf(ax0, bx0), ey0 = fminf(ay0, by0);
    const float ex1 = fmaxf(ax1, bx1), ey1 = fmaxf(ay1, by1);
    const float areaC = fmaxf(ex1 - ex0, 0.f) * fmaxf(ey1 - ey0, 0.f);
    const float giou = iou - (areaC - uni) / areaC;

    return 5.f * l1 + cls - 2.f * giou;
}

// ---------------------------------------------------------------------------
// Fused kernel: one block per batch.
//  Phase 0: stage logits slice -> LDS (dense coalesced float4).
//  Phase A: diag cost block -> LDS (streaming softmax).
//  Phase B1 (ALL 5 waves): FULL-WIDTH Jacobi auction. Each round deals ALL
//    unassigned rows round-robin across the 5 waves (r13 post-mortem: the old
//    1-row-per-wave round scanned only 5/32 rows -> cap starved the fallback).
//    Bid = 64-bit LDS atomicMax of packed (delta_bits+1)<<32 | (~row):
//    max delta wins, tie -> smallest row; single atomic resolves the column.
//    Invariants: v only decreases, winner edge tight (u=g2), loser u=g1
//    feasible, concurrent v-decreases only add slack -> any round prefix is a
//    valid warm start.
//  Phase B2 (wave 0): r11 deferred-dual Dijkstra for leftovers (exact).
//  Phase C (lanes 0-31): 32 matched CROSS costs (reference quirk:
//    mult[i, q_of_t, arange(T)] gathers against GLOBAL targets 0..31).
// ---------------------------------------------------------------------------
__global__ __launch_bounds__(320) void fused_kernel(
    const float* __restrict__ logits,   // [N,Q,C]
    const float* __restrict__ pboxes,   // [N,Q,4]
    const int*   __restrict__ tlabels,  // [N*T]
    const float* __restrict__ tboxes,   // [N*T,4]
    float* __restrict__ out)            // scalar accumulator (pre-zeroed)
{
    const int b = blockIdx.x;
    const int tid = threadIdx.x;

    extern __shared__ float s_lg[];     // [Qq][LSTRIDE] padded logits, 111600 B
    __shared__ float s_diag[Tt * Qq];   // 38400 B, [t][q]
    __shared__ float s_tb[Tt * 4];      // batch-b targets
    __shared__ int   s_tl[Tt];
    __shared__ int   pairs[Tt];         // q_of_t
    __shared__ float s_v[Qq];           // column duals
    __shared__ float s_u[Tt + 1];       // row duals (1-based)
    __shared__ int   s_colrow[Qq];      // row (1..32) matched to col, 0=free
    __shared__ unsigned long long s_bid64[Qq];  // packed bid, 0=empty
    __shared__ int   s_rj1[Tt + 1];     // per-row scan results (this round)
    __shared__ float s_rg1[Tt + 1], s_rg2[Tt + 1];
    __shared__ unsigned s_mask;         // bit (i-1) -> row i unassigned

    if (tid < Tt * 4) s_tb[tid] = tboxes[b * Tt * 4 + tid];
    if (tid < Tt)     s_tl[tid] = tlabels[b * Tt + tid];
    if (tid < Qq)     { s_v[tid] = 0.f; s_colrow[tid] = 0; }
    if (tid == 0)     s_mask = 0xffffffffu;   // all 32 rows unassigned

    // ---------------- Phase 0: coalesced logits -> LDS ----------------
    {
        const float4* lgb = reinterpret_cast<const float4*>(
            logits + (size_t)b * Qq * Cc);
#pragma unroll 4
        for (int g = tid; g < Qq * 23; g += 320) {
            const float4 v = lgb[g];
            const int r = g / 23, c4 = (g - r * 23) * 4;
            float* dst = &s_lg[r * LSTRIDE + c4];
            dst[0] = v.x; dst[1] = v.y; dst[2] = v.z; dst[3] = v.w;
        }
    }
    __syncthreads();

    // ---------------- Phase A: diag costs into LDS ----------------
    if (tid < Qq) {
        const float* srow = &s_lg[tid * LSTRIDE];
        float mx, inv_s;
        softmax_lds(srow, mx, inv_s);
        const float4 pbv = reinterpret_cast<const float4*>(pboxes)[b * Qq + tid];
#pragma unroll 4
        for (int t = 0; t < Tt; ++t) {
            const float cls = -__expf(srow[s_tl[t]] - mx) * inv_s;
            s_diag[t * Qq + tid] =
                det_cost(pbv.x, pbv.y, pbv.z, pbv.w,
                         s_tb[t * 4 + 0], s_tb[t * 4 + 1],
                         s_tb[t * 4 + 2], s_tb[t * 4 + 3], cls);
        }
    }
    __syncthreads();

    // ------------- Phase B1: full-width auction (all 320 threads) -----------
    {
        const int w = tid >> 6, ln = tid & 63;
        const bool iv4 = (ln + 256) >= Qq;
        for (int round = 0; round < AUCTION_ROUNDS; ++round) {
            const unsigned msk = s_mask;        // uniform (read after barrier)
            if (msk == 0) break;                // uniform exit
            for (int j = tid; j < Qq; j += 320) s_bid64[j] = 0ull;
            __syncthreads();

            // deal ALL unassigned rows: n-th set bit -> wave (n % 5)
            {
                unsigned m = msk; int n = 0;
                while (m) {
                    const int row = __ffs(m);   // 1..32
                    m &= m - 1;
                    if ((n % 5) == w) {
                        const float* rowp = &s_diag[(row - 1) * Qq + ln];
                        float m1 = INFINITY, m2 = INFINITY; int a1 = 0;
                        float c;
                        c = rowp[0]   - s_v[ln];
                        if (c < m1) { m2 = m1; m1 = c; a1 = ln + 1; }   else if (c < m2) m2 = c;
                        c = rowp[64]  - s_v[ln + 64];
                        if (c < m1) { m2 = m1; m1 = c; a1 = ln + 65; }  else if (c < m2) m2 = c;
                        c = rowp[128] - s_v[ln + 128];
                        if (c < m1) { m2 = m1; m1 = c; a1 = ln + 129; } else if (c < m2) m2 = c;
                        c = rowp[192] - s_v[ln + 192];
                        if (c < m1) { m2 = m1; m1 = c; a1 = ln + 193; } else if (c < m2) m2 = c;
                        c = iv4 ? INFINITY : (rowp[256] - s_v[ln + 256]);
                        if (c < m1) { m2 = m1; m1 = c; a1 = ln + 257; } else if (c < m2) m2 = c;

                        const float g1 = wave_min_bcast(m1);
                        const unsigned long long mk = __ballot(m1 == g1);
                        const int src = __ffsll((long long)mk) - 1;
                        const float cand2 = (ln == src) ? m2 : m1;  // global 2nd min
                        const float g2 = wave_min_bcast(cand2);
                        const int j1 = __builtin_amdgcn_readlane(a1, src);
                        if (ln == 0) {
                            s_rj1[row] = j1; s_rg1[row] = g1; s_rg2[row] = g2;
                            const unsigned long long pk =
                                ((unsigned long long)(__float_as_uint(g2 - g1) + 1u) << 32)
                                | (unsigned)(0xffffffffu - (unsigned)row);
                            atomicMax(&s_bid64[j1 - 1], pk);
                        }
                    }
                    ++n;
                }
            }
            __syncthreads();

            // resolution: one thread per unassigned row
            if (tid < Tt && (msk & (1u << tid))) {
                const int row = tid + 1;
                const int j1 = s_rj1[row];
                const float g1 = s_rg1[row], g2 = s_rg2[row];
                const unsigned long long mypk =
                    ((unsigned long long)(__float_as_uint(g2 - g1) + 1u) << 32)
                    | (unsigned)(0xffffffffu - (unsigned)row);
                if (s_bid64[j1 - 1] == mypk) {        // unique winner of col j1
                    const int old = s_colrow[j1 - 1];
                    s_colrow[j1 - 1] = row;
                    s_v[j1 - 1] -= (g2 - g1);
                    s_u[row] = g2;                    // tight + feasible
                    atomicAnd(&s_mask, ~(1u << tid));
                    if (old) atomicOr(&s_mask, 1u << (old - 1));
                } else {
                    s_u[row] = g1;                    // feasible for fallback
                }
            }
            __syncthreads();
        }
    }

    if (tid >= 64) return;            // waves 1-4 done; wave 0 below
    const int lane = tid;
    const bool inval4 = (lane + 256) >= Qq;

    // load duals/matching into wave-0 registers
    float u_reg = (lane >= 1 && lane <= Tt) ? s_u[lane] : 0.f;
    float v_r[KCOLS]; int p_r[KCOLS];
#pragma unroll
    for (int k = 0; k < KCOLS; ++k) {
        const int j = lane + 64 * k;
        v_r[k] = (j < Qq) ? s_v[j] : 0.f;
        p_r[k] = (j < Qq) ? s_colrow[j] : 0;
    }

    // ---- Phase B2: Dijkstra fallback (r11 engine) for any leftovers ----
    for (unsigned rem = s_mask; rem; rem &= rem - 1) {
        const int i = __ffs(rem);     // row index 1..32

        float minv_r[KCOLS], vmask[KCOLS], am[KCOLS];
        int way_r[KCOLS];
#pragma unroll
        for (int k = 0; k < KCOLS; ++k) {
            minv_r[k] = FLT_MAX; way_r[k] = 0;
            const bool inv = (k == 4) && inval4;
            vmask[k] = inv ? -INFINITY : v_r[k];
            am[k]    = inv ?  INFINITY : 0.f;
        }
        float markg = 0.f;
        int   ent = 0;
        int   j0 = 0, i0 = i;
        float du = 0.f - readlane_f(u_reg, i);   // dent(0) - u[i]
        int   jfinal = 0;
        float Dfinal = 0.f;

        const float* rowp = &s_diag[(i0 - 1) * Qq + lane];
        float c0 = rowp[0], c1 = rowp[64], c2 = rowp[128], c3 = rowp[192],
              c4 = rowp[256];

        while (true) {
            const float cc[KCOLS] = {c0, c1, c2, c3, c4};
            float sv[KCOLS];
#pragma unroll
            for (int k = 0; k < KCOLS; ++k) {
                const float cur = (cc[k] + du) - vmask[k];  // used/invalid -> +inf
                const bool lt = cur < minv_r[k];
                way_r[k]  = lt ? j0  : way_r[k];
                minv_r[k] = lt ? cur : minv_r[k];
                sv[k] = minv_r[k] + am[k];
            }
            float val = sv[0];
            int   kb  = 0;
#pragma unroll
            for (int k = 1; k < KCOLS; ++k)
                if (sv[k] < val) { val = sv[k]; kb = k; }

            const float gmin = wave_min_bcast(val);
            const unsigned long long mask = __ballot(val == gmin);
            const int src = __ffsll((long long)mask) - 1;
            const int colid = lane + 1 + (kb << 6);
            const int pk = (sel5i(p_r, kb) << 16) | colid;
            const int got = __builtin_amdgcn_readlane(pk, src);
            const int j1   = got & 0xffff;
            const int rowm = got >> 16;

            const int k1 = (j1 - 1) >> 6;
            const bool own = (lane == ((j1 - 1) & 63));
#pragma unroll
            for (int k = 0; k < KCOLS; ++k)
                if (own && k == k1) { vmask[k] = -INFINITY; am[k] = INFINITY; }

            if (rowm == 0) { jfinal = j1; Dfinal = gmin; break; }

            i0 = rowm; j0 = j1;
            rowp = &s_diag[(i0 - 1) * Qq + lane];
            c0 = rowp[0]; c1 = rowp[64]; c2 = rowp[128]; c3 = rowp[192];
            c4 = rowp[256];
            du = gmin - readlane_f(u_reg, i0);
            markg = (lane == rowm) ? gmin : markg;
            ent   = (lane == rowm) ? 1    : ent;
        }

#pragma unroll
        for (int k = 0; k < KCOLS; ++k) {
            bool usedk = (am[k] == INFINITY);
            if (k == 4) usedk = usedk && !inval4;
            v_r[k] -= usedk ? (Dfinal - minv_r[k]) : 0.f;
        }
        u_reg += (lane == i) ? Dfinal : (ent ? (Dfinal - markg) : 0.f);

        int jj = jfinal;
        while (jj) {
            const int ow = (jj - 1) & 63, kk = (jj - 1) >> 6;
            const int jprev = __builtin_amdgcn_readlane(sel5i(way_r, kk), ow);
            int pnew;
            if (jprev == 0) pnew = i;
            else pnew = __builtin_amdgcn_readlane(sel5i(p_r, (jprev - 1) >> 6),
                                                  (jprev - 1) & 63);
            const bool own = (lane == ow);
#pragma unroll
            for (int k = 0; k < KCOLS; ++k) if (own && k == kk) p_r[k] = pnew;
            jj = jprev;
        }
    }

    // publish assignment: q_of_t
#pragma unroll
    for (int k = 0; k < KCOLS; ++k)
        if (p_r[k]) pairs[p_r[k] - 1] = lane + 64 * k;
    __threadfence_block();

    // ---------------- Phase C: 32 matched cross costs ----------------
    float part = 0.f;
    if (lane < Tt) {
        const int q = pairs[lane];                        // matched query
        const float* srow = &s_lg[q * LSTRIDE];
        float mx, inv_s;
        softmax_lds(srow, mx, inv_s);                      // identical path to phase A
        const float4 pbv = reinterpret_cast<const float4*>(pboxes)[b * Qq + q];
        const float4 tbv = reinterpret_cast<const float4*>(tboxes)[lane];  // GLOBAL t=lane
        const float cls = -__expf(srow[tlabels[lane]] - mx) * inv_s;
        part = det_cost(pbv.x, pbv.y, pbv.z, pbv.w,
                        tbv.x, tbv.y, tbv.z, tbv.w, cls);
    }
    for (int off = 32; off > 0; off >>= 1) part += __shfl_down(part, off);
    if (lane == 0) atomicAdd(out, part);
}

extern "C" void kernel_launch(void* const* d_in, const int* in_sizes, int n_in,
                              void* d_out, int out_size, void* d_ws, size_t ws_size,
                              hipStream_t stream) {
    const float* logits  = (const float*)d_in[0];   // [32,300,92] f32
    const float* pboxes  = (const float*)d_in[1];   // [32,300,4]  f32
    const int*   tlabels = (const int*)d_in[2];     // [1024]      int
    const float* tboxes  = (const float*)d_in[3];   // [1024,4]    f32
    float* out = (float*)d_out;                     // scalar f32

    (void)hipMemsetAsync(out, 0, sizeof(float), stream);
    const size_t lg_bytes = (size_t)Qq * LSTRIDE * sizeof(float);  // 111600 B
    fused_kernel<<<Nn, 320, lg_bytes, stream>>>(logits, pboxes, tlabels, tboxes, out);
}